// Round 7
// baseline (1492.075 us; speedup 1.0000x reference)
//
#include <hip/hip_runtime.h>
#include <hip/hip_bf16.h>

#define B_ 4
#define H_ 16
#define L_ 2048
#define D_ 128
#define BH_ 64

typedef __attribute__((ext_vector_type(8))) _Float16 f16x8;
typedef __attribute__((ext_vector_type(4))) float f32x4;
typedef __attribute__((ext_vector_type(16))) float f32x16;
typedef __attribute__((ext_vector_type(2))) unsigned u32x2;

#define L2E 1.44269504088896f

// Returns L2E*gelu(v) - m  (negm = -m), exact-erf via A&S 7.1.26, branch-free.
// Identity: L2E*gelu(v) = max(L2E*v, 0) - |0.5*L2E*v| * poly(t) * exp2(-L2E*v^2/2)
// (uses hv + |hv|*(1 - pe) = max(2hv,0) - |hv|*pe). Folding -m into the relu
// term removes the later softmax subtract AND the copysign.
__device__ __forceinline__ float gelu_m(float v, float negm) {
  float x    = v * 0.70710678118f;
  float ax   = __builtin_fabsf(x);
  float t    = __builtin_amdgcn_rcpf(__builtin_fmaf(0.3275911f, ax, 1.0f));
  float poly = t * __builtin_fmaf(t,
                 __builtin_fmaf(t,
                   __builtin_fmaf(t,
                     __builtin_fmaf(t, 1.061405429f, -1.453152027f),
                   1.421413741f),
                 -0.284496736f),
               0.254829592f);
  float nv   = -0.72134752f * v;                       // -0.5*L2E*v
  float e    = __builtin_amdgcn_exp2f(nv * v);         // exp2(-L2E*x^2)
  float hva  = __builtin_fabsf(nv);                    // |0.5*L2E*v|
  float relm = fmaxf(__builtin_fmaf(1.44269504f, v, negm), negm);
  float pe   = poly * e;
  return __builtin_fmaf(hva, -pe, relm);
}

__device__ __forceinline__ void gl2lds16(const void* g, void* l) {
  __builtin_amdgcn_global_load_lds(
      (const __attribute__((address_space(1))) void*)g,
      (__attribute__((address_space(3))) void*)l, 16, 0, 0);
}

__device__ __forceinline__ unsigned pkrtz(float a, float b) {
  auto t = __builtin_amdgcn_cvt_pkrtz(a, b);   // __fp16 ext_vector(2)
  return __builtin_bit_cast(unsigned, t);
}

// ---------------------------------------------------------------------------
// Kernel 0: one-time W1,W2 f32 -> f16 (scratch in d_out head; attn overwrites).
// ---------------------------------------------------------------------------
__global__ __launch_bounds__(256) void wcvt_kernel(
    const float* __restrict__ W1, const float* __restrict__ W2,
    _Float16* __restrict__ Wh1, _Float16* __restrict__ Wh2)
{
  int i = blockIdx.x * 256 + threadIdx.x;
  Wh1[i] = (_Float16)W1[i];
  Wh2[i] = (_Float16)W2[i];
}

// ---------------------------------------------------------------------------
// Kernel 1: q/k projections (f16 MFMA, f32 accum, +bias) and x -> V^T (f16).
// ---------------------------------------------------------------------------
__global__ __launch_bounds__(256) void proj_tr_kernel(
    const float* __restrict__ x,
    const _Float16* __restrict__ Wh1, const float* __restrict__ b1,
    const _Float16* __restrict__ Wh2, const float* __restrict__ b2,
    _Float16* __restrict__ Qb, _Float16* __restrict__ Kb,
    _Float16* __restrict__ VT)
{
  const int tid  = threadIdx.x;
  const int wave = tid >> 6;
  const int lane = tid & 63;
  const int lhi  = lane >> 4;
  const int llo  = lane & 15;
  const int r0   = blockIdx.x * 64;
  const int wr0  = r0 + wave * 16;

  f16x8 a[4];
#pragma unroll
  for (int ks = 0; ks < 4; ++ks) {
    const float* p = x + (size_t)(wr0 + llo) * D_ + lhi * 8 + ks * 32;
    f16x8 t;
#pragma unroll
    for (int e = 0; e < 8; ++e) t[e] = (_Float16)p[e];
    a[ks] = t;
  }

  f32x4 accq[8], acck[8];
#pragma unroll
  for (int n = 0; n < 8; ++n) {
    accq[n] = (f32x4){0.f, 0.f, 0.f, 0.f};
    acck[n] = (f32x4){0.f, 0.f, 0.f, 0.f};
  }

#pragma unroll
  for (int n = 0; n < 8; ++n) {
    const int e = n * 16 + llo;
#pragma unroll
    for (int ks = 0; ks < 4; ++ks) {
      f16x8 w1f = *(const f16x8*)(Wh1 + (size_t)e * D_ + lhi * 8 + ks * 32);
      f16x8 w2f = *(const f16x8*)(Wh2 + (size_t)e * D_ + lhi * 8 + ks * 32);
      accq[n] = __builtin_amdgcn_mfma_f32_16x16x32_f16(a[ks], w1f, accq[n], 0, 0, 0);
      acck[n] = __builtin_amdgcn_mfma_f32_16x16x32_f16(a[ks], w2f, acck[n], 0, 0, 0);
    }
  }

#pragma unroll
  for (int n = 0; n < 8; ++n) {
    const int e = n * 16 + llo;
    const float bias1 = b1[e];
    const float bias2 = b2[e];
#pragma unroll
    for (int r = 0; r < 4; ++r) {
      const size_t row = (size_t)wr0 + lhi * 4 + r;
      Qb[row * D_ + e] = (_Float16)(accq[n][r] + bias1);
      Kb[row * D_ + e] = (_Float16)(acck[n][r] + bias2);
    }
  }

  const int bh = r0 / L_;
  const int l0 = r0 % L_;
  const int d  = tid & 127;
  const int rh = tid >> 7;
  _Float16* dst = VT + (size_t)bh * D_ * L_ + (size_t)d * L_ + l0 + rh * 32;
#pragma unroll
  for (int j = 0; j < 4; ++j) {
    f16x8 t;
#pragma unroll
    for (int e = 0; e < 8; ++e)
      t[e] = (_Float16)x[(size_t)(r0 + rh * 32 + j * 8 + e) * D_ + d];
    *(f16x8*)(dst + j * 8) = t;
  }
}

// ---------------------------------------------------------------------------
// Kernel 2: fused gelu(QK^T)->softmax->@V flash attention, 32x32x16 MFMA.
// 8 waves x 32 q-rows = 256 q/block; K,V LDS-staged (dbuf, gl2lds, swizzled);
// swapped QK^T -> lane-local softmax (m folded into GELU); T12 in-register
// P->A-frag; defer-max; t-loop unrolled x2 so `cur` folds into ds offsets.
// ---------------------------------------------------------------------------
__global__ __launch_bounds__(512, 4) void attn_kernel(
    const _Float16* __restrict__ Qb, const _Float16* __restrict__ Kb,
    const _Float16* __restrict__ VT, float* __restrict__ out)
{
  __shared__ _Float16 Ks[2][64 * 128];   // 2 x 16KB
  __shared__ _Float16 Vs[2][128 * 64];   // 2 x 16KB

  const int tid  = threadIdx.x;
  const int wave = tid >> 6;      // 0..7
  const int lane = tid & 63;
  const int l5   = lane & 31;
  const int hi   = lane >> 5;

  // XCD-aware swizzle: 512 blocks, 8 XCDs -> 8 whole heads per XCD.
  const int bid = blockIdx.x;
  const int blk = (bid & 7) * 64 + (bid >> 3);
  const int bh  = blk >> 3;            // 8 q-blocks (256 rows) per head
  const int q0  = (blk & 7) * 256;
  const int b   = bh >> 4;
  const int h   = bh & 15;
  const int wq0 = q0 + wave * 32;

  const char* KheadB = (const char*)(Kb + (size_t)bh * L_ * D_);
  const char* VheadB = (const char*)(VT + (size_t)bh * D_ * L_);

  // ---- staging constants (16KB tile = 8 waves x 2 calls x 1KB each) ----
  int klds[2], ksrc[2], vlds[2], vsrc[2];
#pragma unroll
  for (int c = 0; c < 2; ++c) {
    const int wc = wave * 2 + c;
    klds[c] = wc * 1024;                               // wave-uniform LDS dest
    {
      const int l  = wc * 4 + (lane >> 4);             // K-tile row
      const int c0 = (lane & 15) * 8;                  // col halves
      ksrc[c] = l * 256 + 2 * (c0 ^ ((l & 7) << 3));   // pre-swizzled source
    }
    vlds[c] = wc * 1024;
    {
      const int d  = wc * 8 + (lane >> 3);             // V-tile row (d)
      const int c0 = (lane & 7) * 8;
      vsrc[c] = d * 4096 + 2 * (c0 ^ ((d & 7) << 3));
    }
  }
  const int kvswz = (l5 & 7) << 3;                     // read-side XOR (halves)

  // Q fragments (B-operand of swapped QK^T): j = l5 = q-row, k = s*16+hi*8+e
  f16x8 qf[8];
#pragma unroll
  for (int s = 0; s < 8; ++s)
    qf[s] = *(const f16x8*)(Qb + ((size_t)bh * L_ + wq0 + l5) * D_ + s * 16 + hi * 8);

  f32x16 accO[4];
#pragma unroll
  for (int n = 0; n < 4; ++n)
#pragma unroll
    for (int r = 0; r < 16; ++r) accO[n][r] = 0.f;
  float negm = 64.f;   // -m; m init -64 (any gelu >= -0.36 in bits; avoids
                       // catastrophic cancellation in the deferred-m update)
  float l = 0.f;

  // ---- prologue: stage tile 0 ----
#pragma unroll
  for (int c = 0; c < 2; ++c) {
    gl2lds16(KheadB + ksrc[c], (char*)&Ks[0][0] + klds[c]);
    gl2lds16(VheadB + vsrc[c], (char*)&Vs[0][0] + vlds[c]);
  }
  __syncthreads();

#pragma unroll 2
  for (int t = 0; t < L_ / 64; ++t) {
    const int cur = t & 1;          // folds to 0/1 under unroll-by-2
    // ---- prefetch next K/V tile (in flight across the tile body) ----
    if (t + 1 < L_ / 64) {
      const char* kt_ = KheadB + (size_t)(t + 1) * 64 * 256;
      const char* vt_ = VheadB + (size_t)(t + 1) * 128;
#pragma unroll
      for (int c = 0; c < 2; ++c) {
        gl2lds16(kt_ + ksrc[c], (char*)&Ks[cur ^ 1][0] + klds[c]);
        gl2lds16(vt_ + vsrc[c], (char*)&Vs[cur ^ 1][0] + vlds[c]);
      }
    }
    const _Float16* Kcur = &Ks[cur][0];
    const _Float16* Vcur = &Vs[cur][0];

#pragma unroll
    for (int kb = 0; kb < 2; ++kb) {
      // ---- S^T = K Q^T : lane holds q=l5, k-rows (r&3)+8*(r>>2)+4*hi+kb*32
      f32x16 sT;
#pragma unroll
      for (int r = 0; r < 16; ++r) sT[r] = 0.f;
      __builtin_amdgcn_s_setprio(1);
#pragma unroll
      for (int s = 0; s < 8; ++s) {
        f16x8 kf = *(const f16x8*)(Kcur + (kb * 32 + l5) * 128 +
                                   ((s * 16 + hi * 8) ^ kvswz));
        sT = __builtin_amdgcn_mfma_f32_32x32x16_f16(kf, qf[s], sT, 0, 0, 0);
      }
      __builtin_amdgcn_s_setprio(0);

      // ---- GELU with -m folded in: gm[r] = L2E*gelu(sT[r]) - m ----
      float gm[16];
#pragma unroll
      for (int r = 0; r < 16; ++r) gm[r] = gelu_m(sT[r], negm);

      // ---- subtile max (max3-shaped chain) + partner half ----
      float tm = fmaxf(fmaxf(gm[0], gm[1]), gm[2]);
      tm = fmaxf(fmaxf(tm, gm[3]),  gm[4]);
      tm = fmaxf(fmaxf(tm, gm[5]),  gm[6]);
      tm = fmaxf(fmaxf(tm, gm[7]),  gm[8]);
      tm = fmaxf(fmaxf(tm, gm[9]),  gm[10]);
      tm = fmaxf(fmaxf(tm, gm[11]), gm[12]);
      tm = fmaxf(fmaxf(tm, gm[13]), gm[14]);
      tm = fmaxf(tm, gm[15]);
      tm = fmaxf(tm, __shfl_xor(tm, 32));

      // ---- online softmax with defer-max (THR = 8 nats = 11.54 bits) ----
      float p[16];
      float ts;
      if (__all(tm <= 11.5415603f)) {
#pragma unroll
        for (int r = 0; r < 16; ++r) p[r] = __builtin_amdgcn_exp2f(gm[r]);
        float a0 = p[0]+p[1],   a1 = p[2]+p[3],   a2 = p[4]+p[5],   a3 = p[6]+p[7];
        float a4 = p[8]+p[9],   a5 = p[10]+p[11], a6 = p[12]+p[13], a7 = p[14]+p[15];
        ts = ((a0+a1)+(a2+a3)) + ((a4+a5)+(a6+a7));
        ts += __shfl_xor(ts, 32);
        l += ts;
      } else {
        float dm = fmaxf(tm, 0.f);
        negm -= dm;
        float sc = __builtin_amdgcn_exp2f(-dm);
#pragma unroll
        for (int r = 0; r < 16; ++r) p[r] = __builtin_amdgcn_exp2f(gm[r] - dm);
        float a0 = p[0]+p[1],   a1 = p[2]+p[3],   a2 = p[4]+p[5],   a3 = p[6]+p[7];
        float a4 = p[8]+p[9],   a5 = p[10]+p[11], a6 = p[12]+p[13], a7 = p[14]+p[15];
        ts = ((a0+a1)+(a2+a3)) + ((a4+a5)+(a6+a7));
        ts += __shfl_xor(ts, 32);
        l = __builtin_fmaf(l, sc, ts);
        float scr[16];
#pragma unroll
        for (int r = 0; r < 16; ++r)
          scr[r] = __shfl(sc, (r & 3) + 8 * (r >> 2) + 4 * hi);
#pragma unroll
        for (int n = 0; n < 4; ++n)
#pragma unroll
          for (int r = 0; r < 16; ++r) accO[n][r] *= scr[r];
      }

      // ---- P -> PV A-fragments in-register (T12: cvt_pkrtz + permlane32) --
      unsigned pk01 = pkrtz(p[0], p[1]),   pk23 = pkrtz(p[2], p[3]);
      unsigned pk45 = pkrtz(p[4], p[5]),   pk67 = pkrtz(p[6], p[7]);
      unsigned pk89 = pkrtz(p[8], p[9]),   pkAB = pkrtz(p[10], p[11]);
      unsigned pkCD = pkrtz(p[12], p[13]), pkEF = pkrtz(p[14], p[15]);
      u32x2 r0 = __builtin_amdgcn_permlane32_swap(pk01, pk45, false, false);
      u32x2 r1 = __builtin_amdgcn_permlane32_swap(pk23, pk67, false, false);
      u32x2 r2 = __builtin_amdgcn_permlane32_swap(pk89, pkCD, false, false);
      u32x2 r3 = __builtin_amdgcn_permlane32_swap(pkAB, pkEF, false, false);
      union { unsigned u[4]; f16x8 v; } A0c, A1c;
      A0c.u[0] = r0[0]; A0c.u[1] = r1[0]; A0c.u[2] = r0[1]; A0c.u[3] = r1[1];
      A1c.u[0] = r2[0]; A1c.u[1] = r3[0]; A1c.u[2] = r2[1]; A1c.u[3] = r3[1];

      // ---- O += P @ V ----
      __builtin_amdgcn_s_setprio(1);
#pragma unroll
      for (int n = 0; n < 4; ++n) {
        f16x8 vf0 = *(const f16x8*)(Vcur + (n * 32 + l5) * 64 +
                                    ((kb * 32 + hi * 8) ^ kvswz));
        accO[n] = __builtin_amdgcn_mfma_f32_32x32x16_f16(A0c.v, vf0, accO[n], 0, 0, 0);
        f16x8 vf1 = *(const f16x8*)(Vcur + (n * 32 + l5) * 64 +
                                    ((kb * 32 + 16 + hi * 8) ^ kvswz));
        accO[n] = __builtin_amdgcn_mfma_f32_32x32x16_f16(A1c.v, vf1, accO[n], 0, 0, 0);
      }
      __builtin_amdgcn_s_setprio(0);
    }

    __syncthreads();   // waves done with cur; prefetch into cur^1 landed
  }

  // ---- epilogue: O[q][d] / l[q]; q = (r&3)+8*(r>>2)+4*hi, d = n*32+l5 ----
  float linv = __builtin_amdgcn_rcpf(l);
  float lb[16];
#pragma unroll
  for (int r = 0; r < 16; ++r)
    lb[r] = __shfl(linv, (r & 3) + 8 * (r >> 2) + 4 * hi);
#pragma unroll
  for (int n = 0; n < 4; ++n)
#pragma unroll
    for (int r = 0; r < 16; ++r) {
      const int i = wq0 + (r & 3) + 8 * (r >> 2) + 4 * hi;
      out[((size_t)(b * L_ + i) * H_ + h) * D_ + n * 32 + l5] = accO[n][r] * lb[r];
    }
}

extern "C" void kernel_launch(void* const* d_in, const int* in_sizes, int n_in,
                              void* d_out, int out_size, void* d_ws, size_t ws_size,
                              hipStream_t stream) {
  const float* x  = (const float*)d_in[0];
  const float* W1 = (const float*)d_in[1];
  const float* b1 = (const float*)d_in[2];
  const float* W2 = (const float*)d_in[3];
  const float* b2 = (const float*)d_in[4];
  float* out = (float*)d_out;

  const size_t N = (size_t)BH_ * L_ * D_;
  _Float16* Qb = (_Float16*)d_ws;
  _Float16* Kb = Qb + N;
  _Float16* VT = Kb + N;

  _Float16* Wh1 = (_Float16*)d_out;          // scratch; attn overwrites out
  _Float16* Wh2 = Wh1 + D_ * D_;

  wcvt_kernel<<<64, 256, 0, stream>>>(W1, W2, Wh1, Wh2);
  proj_tr_kernel<<<(BH_ * L_) / 64, 256, 0, stream>>>(x, Wh1, b1, Wh2, b2, Qb, Kb, VT);
  attn_kernel<<<BH_ * (L_ / 256), 512, 0, stream>>>(Qb, Kb, VT, out);
}

// Round 8
// 383.395 us; speedup vs baseline: 3.8917x; 3.8917x over previous
//
#include <hip/hip_runtime.h>
#include <hip/hip_bf16.h>

#define B_ 4
#define H_ 16
#define L_ 2048
#define D_ 128
#define BH_ 64

typedef __attribute__((ext_vector_type(8))) _Float16 f16x8;
typedef __attribute__((ext_vector_type(4))) float f32x4;
typedef __attribute__((ext_vector_type(16))) float f32x16;
typedef __attribute__((ext_vector_type(2))) unsigned u32x2;

#define L2E 1.44269504088896f

// Returns L2E*gelu(v) - m  (negm = -m), exact-erf via A&S 7.1.26, branch-free.
// L2E*gelu(v) = max(L2E*v, 0) - |0.5*L2E*v| * poly(t) * exp2(-L2E*v^2/2).
// Folding -m into the relu term removes the softmax subtract AND the copysign.
__device__ __forceinline__ float gelu_m(float v, float negm) {
  float x    = v * 0.70710678118f;
  float ax   = __builtin_fabsf(x);
  float t    = __builtin_amdgcn_rcpf(__builtin_fmaf(0.3275911f, ax, 1.0f));
  float poly = t * __builtin_fmaf(t,
                 __builtin_fmaf(t,
                   __builtin_fmaf(t,
                     __builtin_fmaf(t, 1.061405429f, -1.453152027f),
                   1.421413741f),
                 -0.284496736f),
               0.254829592f);
  float nv   = -0.72134752f * v;                       // -0.5*L2E*v
  float e    = __builtin_amdgcn_exp2f(nv * v);         // exp2(-L2E*x^2)
  float hva  = __builtin_fabsf(nv);                    // |0.5*L2E*v|
  float relm = fmaxf(__builtin_fmaf(1.44269504f, v, negm), negm);
  float pe   = poly * e;
  return __builtin_fmaf(hva, -pe, relm);
}

__device__ __forceinline__ void gl2lds16(const void* g, void* l) {
  __builtin_amdgcn_global_load_lds(
      (const __attribute__((address_space(1))) void*)g,
      (__attribute__((address_space(3))) void*)l, 16, 0, 0);
}

__device__ __forceinline__ unsigned pkrtz(float a, float b) {
  auto t = __builtin_amdgcn_cvt_pkrtz(a, b);   // __fp16 ext_vector(2)
  return __builtin_bit_cast(unsigned, t);
}

// ---------------------------------------------------------------------------
// Kernel 0: one-time W1,W2 f32 -> f16 (scratch in d_out head; attn overwrites).
// ---------------------------------------------------------------------------
__global__ __launch_bounds__(256) void wcvt_kernel(
    const float* __restrict__ W1, const float* __restrict__ W2,
    _Float16* __restrict__ Wh1, _Float16* __restrict__ Wh2)
{
  int i = blockIdx.x * 256 + threadIdx.x;
  Wh1[i] = (_Float16)W1[i];
  Wh2[i] = (_Float16)W2[i];
}

// ---------------------------------------------------------------------------
// Kernel 1: q/k projections (f16 MFMA, f32 accum, +bias) and x -> V^T (f16).
// ---------------------------------------------------------------------------
__global__ __launch_bounds__(256) void proj_tr_kernel(
    const float* __restrict__ x,
    const _Float16* __restrict__ Wh1, const float* __restrict__ b1,
    const _Float16* __restrict__ Wh2, const float* __restrict__ b2,
    _Float16* __restrict__ Qb, _Float16* __restrict__ Kb,
    _Float16* __restrict__ VT)
{
  const int tid  = threadIdx.x;
  const int wave = tid >> 6;
  const int lane = tid & 63;
  const int lhi  = lane >> 4;
  const int llo  = lane & 15;
  const int r0   = blockIdx.x * 64;
  const int wr0  = r0 + wave * 16;

  f16x8 a[4];
#pragma unroll
  for (int ks = 0; ks < 4; ++ks) {
    const float* p = x + (size_t)(wr0 + llo) * D_ + lhi * 8 + ks * 32;
    f16x8 t;
#pragma unroll
    for (int e = 0; e < 8; ++e) t[e] = (_Float16)p[e];
    a[ks] = t;
  }

  f32x4 accq[8], acck[8];
#pragma unroll
  for (int n = 0; n < 8; ++n) {
    accq[n] = (f32x4){0.f, 0.f, 0.f, 0.f};
    acck[n] = (f32x4){0.f, 0.f, 0.f, 0.f};
  }

#pragma unroll
  for (int n = 0; n < 8; ++n) {
    const int e = n * 16 + llo;
#pragma unroll
    for (int ks = 0; ks < 4; ++ks) {
      f16x8 w1f = *(const f16x8*)(Wh1 + (size_t)e * D_ + lhi * 8 + ks * 32);
      f16x8 w2f = *(const f16x8*)(Wh2 + (size_t)e * D_ + lhi * 8 + ks * 32);
      accq[n] = __builtin_amdgcn_mfma_f32_16x16x32_f16(a[ks], w1f, accq[n], 0, 0, 0);
      acck[n] = __builtin_amdgcn_mfma_f32_16x16x32_f16(a[ks], w2f, acck[n], 0, 0, 0);
    }
  }

#pragma unroll
  for (int n = 0; n < 8; ++n) {
    const int e = n * 16 + llo;
    const float bias1 = b1[e];
    const float bias2 = b2[e];
#pragma unroll
    for (int r = 0; r < 4; ++r) {
      const size_t row = (size_t)wr0 + lhi * 4 + r;
      Qb[row * D_ + e] = (_Float16)(accq[n][r] + bias1);
      Kb[row * D_ + e] = (_Float16)(acck[n][r] + bias2);
    }
  }

  const int bh = r0 / L_;
  const int l0 = r0 % L_;
  const int d  = tid & 127;
  const int rh = tid >> 7;
  _Float16* dst = VT + (size_t)bh * D_ * L_ + (size_t)d * L_ + l0 + rh * 32;
#pragma unroll
  for (int j = 0; j < 4; ++j) {
    f16x8 t;
#pragma unroll
    for (int e = 0; e < 8; ++e)
      t[e] = (_Float16)x[(size_t)(r0 + rh * 32 + j * 8 + e) * D_ + d];
    *(f16x8*)(dst + j * 8) = t;
  }
}

// ---------------------------------------------------------------------------
// Kernel 2: fused gelu(QK^T)->softmax->@V flash attention, 32x32x16 MFMA.
// 8 waves x 32 q-rows = 256 q/block; K,V LDS-staged (dbuf, gl2lds, swizzled);
// swapped QK^T -> lane-local softmax (m folded into GELU); T12 in-register
// P->A-frag; defer-max. Plain launch_bounds(512): R7's (512,4) forced
// VGPR=64 + full accumulator spill (WRITE_SIZE 66MB->3.4GB) -- never again.
// ---------------------------------------------------------------------------
__global__ __launch_bounds__(512) void attn_kernel(
    const _Float16* __restrict__ Qb, const _Float16* __restrict__ Kb,
    const _Float16* __restrict__ VT, float* __restrict__ out)
{
  __shared__ _Float16 Ks[2][64 * 128];   // 2 x 16KB
  __shared__ _Float16 Vs[2][128 * 64];   // 2 x 16KB

  const int tid  = threadIdx.x;
  const int wave = tid >> 6;      // 0..7
  const int lane = tid & 63;
  const int l5   = lane & 31;
  const int hi   = lane >> 5;

  // XCD-aware swizzle: 512 blocks, 8 XCDs -> 8 whole heads per XCD.
  const int bid = blockIdx.x;
  const int blk = (bid & 7) * 64 + (bid >> 3);
  const int bh  = blk >> 3;            // 8 q-blocks (256 rows) per head
  const int q0  = (blk & 7) * 256;
  const int b   = bh >> 4;
  const int h   = bh & 15;
  const int wq0 = q0 + wave * 32;

  const char* KheadB = (const char*)(Kb + (size_t)bh * L_ * D_);
  const char* VheadB = (const char*)(VT + (size_t)bh * D_ * L_);

  // ---- staging constants (16KB tile = 8 waves x 2 calls x 1KB each) ----
  int klds[2], ksrc[2], vlds[2], vsrc[2];
#pragma unroll
  for (int c = 0; c < 2; ++c) {
    const int wc = wave * 2 + c;
    klds[c] = wc * 1024;                               // wave-uniform LDS dest
    {
      const int l  = wc * 4 + (lane >> 4);             // K-tile row
      const int c0 = (lane & 15) * 8;                  // col halves
      ksrc[c] = l * 256 + 2 * (c0 ^ ((l & 7) << 3));   // pre-swizzled source
    }
    vlds[c] = wc * 1024;
    {
      const int d  = wc * 8 + (lane >> 3);             // V-tile row (d)
      const int c0 = (lane & 7) * 8;
      vsrc[c] = d * 4096 + 2 * (c0 ^ ((d & 7) << 3));
    }
  }
  const int kvswz = (l5 & 7) << 3;                     // read-side XOR (halves)

  // Q fragments (B-operand of swapped QK^T): j = l5 = q-row, k = s*16+hi*8+e
  f16x8 qf[8];
#pragma unroll
  for (int s = 0; s < 8; ++s)
    qf[s] = *(const f16x8*)(Qb + ((size_t)bh * L_ + wq0 + l5) * D_ + s * 16 + hi * 8);

  f32x16 accO[4];
#pragma unroll
  for (int n = 0; n < 4; ++n)
#pragma unroll
    for (int r = 0; r < 16; ++r) accO[n][r] = 0.f;
  float negm = 64.f;   // -m; m init -64 (avoids cancellation in m updates)
  float l = 0.f;

  // ---- prologue: stage tile 0 ----
#pragma unroll
  for (int c = 0; c < 2; ++c) {
    gl2lds16(KheadB + ksrc[c], (char*)&Ks[0][0] + klds[c]);
    gl2lds16(VheadB + vsrc[c], (char*)&Vs[0][0] + vlds[c]);
  }
  __syncthreads();

  int cur = 0;
  for (int t = 0; t < L_ / 64; ++t) {
    // ---- prefetch next K/V tile (in flight across the tile body) ----
    if (t + 1 < L_ / 64) {
      const char* kt_ = KheadB + (size_t)(t + 1) * 64 * 256;
      const char* vt_ = VheadB + (size_t)(t + 1) * 128;
#pragma unroll
      for (int c = 0; c < 2; ++c) {
        gl2lds16(kt_ + ksrc[c], (char*)&Ks[cur ^ 1][0] + klds[c]);
        gl2lds16(vt_ + vsrc[c], (char*)&Vs[cur ^ 1][0] + vlds[c]);
      }
    }
    const _Float16* Kcur = &Ks[cur][0];
    const _Float16* Vcur = &Vs[cur][0];

#pragma unroll
    for (int kb = 0; kb < 2; ++kb) {
      // ---- S^T = K Q^T : lane holds q=l5, k-rows (r&3)+8*(r>>2)+4*hi+kb*32
      f32x16 sT;
#pragma unroll
      for (int r = 0; r < 16; ++r) sT[r] = 0.f;
      __builtin_amdgcn_s_setprio(1);
#pragma unroll
      for (int s = 0; s < 8; ++s) {
        f16x8 kf = *(const f16x8*)(Kcur + (kb * 32 + l5) * 128 +
                                   ((s * 16 + hi * 8) ^ kvswz));
        sT = __builtin_amdgcn_mfma_f32_32x32x16_f16(kf, qf[s], sT, 0, 0, 0);
      }
      __builtin_amdgcn_s_setprio(0);

      // ---- GELU with -m folded in: gm[r] = L2E*gelu(sT[r]) - m ----
      float gm[16];
#pragma unroll
      for (int r = 0; r < 16; ++r) gm[r] = gelu_m(sT[r], negm);

      // ---- subtile max (max3-shaped chain) + partner half ----
      float tm = fmaxf(fmaxf(gm[0], gm[1]), gm[2]);
      tm = fmaxf(fmaxf(tm, gm[3]),  gm[4]);
      tm = fmaxf(fmaxf(tm, gm[5]),  gm[6]);
      tm = fmaxf(fmaxf(tm, gm[7]),  gm[8]);
      tm = fmaxf(fmaxf(tm, gm[9]),  gm[10]);
      tm = fmaxf(fmaxf(tm, gm[11]), gm[12]);
      tm = fmaxf(fmaxf(tm, gm[13]), gm[14]);
      tm = fmaxf(tm, gm[15]);
      tm = fmaxf(tm, __shfl_xor(tm, 32));

      // ---- online softmax with defer-max (THR = 8 nats = 11.54 bits) ----
      float p[16];
      float ts;
      if (__all(tm <= 11.5415603f)) {
#pragma unroll
        for (int r = 0; r < 16; ++r) p[r] = __builtin_amdgcn_exp2f(gm[r]);
        float a0 = p[0]+p[1],   a1 = p[2]+p[3],   a2 = p[4]+p[5],   a3 = p[6]+p[7];
        float a4 = p[8]+p[9],   a5 = p[10]+p[11], a6 = p[12]+p[13], a7 = p[14]+p[15];
        ts = ((a0+a1)+(a2+a3)) + ((a4+a5)+(a6+a7));
        ts += __shfl_xor(ts, 32);
        l += ts;
      } else {
        float dm = fmaxf(tm, 0.f);
        negm -= dm;
        float sc = __builtin_amdgcn_exp2f(-dm);
#pragma unroll
        for (int r = 0; r < 16; ++r) p[r] = __builtin_amdgcn_exp2f(gm[r] - dm);
        float a0 = p[0]+p[1],   a1 = p[2]+p[3],   a2 = p[4]+p[5],   a3 = p[6]+p[7];
        float a4 = p[8]+p[9],   a5 = p[10]+p[11], a6 = p[12]+p[13], a7 = p[14]+p[15];
        ts = ((a0+a1)+(a2+a3)) + ((a4+a5)+(a6+a7));
        ts += __shfl_xor(ts, 32);
        l = __builtin_fmaf(l, sc, ts);
        float scr[16];
#pragma unroll
        for (int r = 0; r < 16; ++r)
          scr[r] = __shfl(sc, (r & 3) + 8 * (r >> 2) + 4 * hi);
#pragma unroll
        for (int n = 0; n < 4; ++n)
#pragma unroll
          for (int r = 0; r < 16; ++r) accO[n][r] *= scr[r];
      }

      // ---- P -> PV A-fragments in-register (T12: cvt_pkrtz + permlane32) --
      unsigned pk01 = pkrtz(p[0], p[1]),   pk23 = pkrtz(p[2], p[3]);
      unsigned pk45 = pkrtz(p[4], p[5]),   pk67 = pkrtz(p[6], p[7]);
      unsigned pk89 = pkrtz(p[8], p[9]),   pkAB = pkrtz(p[10], p[11]);
      unsigned pkCD = pkrtz(p[12], p[13]), pkEF = pkrtz(p[14], p[15]);
      u32x2 r0 = __builtin_amdgcn_permlane32_swap(pk01, pk45, false, false);
      u32x2 r1 = __builtin_amdgcn_permlane32_swap(pk23, pk67, false, false);
      u32x2 r2 = __builtin_amdgcn_permlane32_swap(pk89, pkCD, false, false);
      u32x2 r3 = __builtin_amdgcn_permlane32_swap(pkAB, pkEF, false, false);
      union { unsigned u[4]; f16x8 v; } A0c, A1c;
      A0c.u[0] = r0[0]; A0c.u[1] = r1[0]; A0c.u[2] = r0[1]; A0c.u[3] = r1[1];
      A1c.u[0] = r2[0]; A1c.u[1] = r3[0]; A1c.u[2] = r2[1]; A1c.u[3] = r3[1];

      // ---- O += P @ V ----
      __builtin_amdgcn_s_setprio(1);
#pragma unroll
      for (int n = 0; n < 4; ++n) {
        f16x8 vf0 = *(const f16x8*)(Vcur + (n * 32 + l5) * 64 +
                                    ((kb * 32 + hi * 8) ^ kvswz));
        accO[n] = __builtin_amdgcn_mfma_f32_32x32x16_f16(A0c.v, vf0, accO[n], 0, 0, 0);
        f16x8 vf1 = *(const f16x8*)(Vcur + (n * 32 + l5) * 64 +
                                    ((kb * 32 + 16 + hi * 8) ^ kvswz));
        accO[n] = __builtin_amdgcn_mfma_f32_32x32x16_f16(A1c.v, vf1, accO[n], 0, 0, 0);
      }
      __builtin_amdgcn_s_setprio(0);
    }

    __syncthreads();   // waves done with cur; prefetch into cur^1 landed
    cur ^= 1;
  }

  // ---- epilogue: O[q][d] / l[q]; q = (r&3)+8*(r>>2)+4*hi, d = n*32+l5 ----
  float linv = __builtin_amdgcn_rcpf(l);
  float lb[16];
#pragma unroll
  for (int r = 0; r < 16; ++r)
    lb[r] = __shfl(linv, (r & 3) + 8 * (r >> 2) + 4 * hi);
#pragma unroll
  for (int n = 0; n < 4; ++n)
#pragma unroll
    for (int r = 0; r < 16; ++r) {
      const int i = wq0 + (r & 3) + 8 * (r >> 2) + 4 * hi;
      out[((size_t)(b * L_ + i) * H_ + h) * D_ + n * 32 + l5] = accO[n][r] * lb[r];
    }
}

extern "C" void kernel_launch(void* const* d_in, const int* in_sizes, int n_in,
                              void* d_out, int out_size, void* d_ws, size_t ws_size,
                              hipStream_t stream) {
  const float* x  = (const float*)d_in[0];
  const float* W1 = (const float*)d_in[1];
  const float* b1 = (const float*)d_in[2];
  const float* W2 = (const float*)d_in[3];
  const float* b2 = (const float*)d_in[4];
  float* out = (float*)d_out;

  const size_t N = (size_t)BH_ * L_ * D_;
  _Float16* Qb = (_Float16*)d_ws;
  _Float16* Kb = Qb + N;
  _Float16* VT = Kb + N;

  _Float16* Wh1 = (_Float16*)d_out;          // scratch; attn overwrites out
  _Float16* Wh2 = Wh1 + D_ * D_;

  wcvt_kernel<<<64, 256, 0, stream>>>(W1, W2, Wh1, Wh2);
  proj_tr_kernel<<<(BH_ * L_) / 64, 256, 0, stream>>>(x, Wh1, b1, Wh2, b2, Qb, Kb, VT);
  attn_kernel<<<BH_ * (L_ / 256), 512, 0, stream>>>(Qb, Kb, VT, out);
}